// Round 7
// baseline (65336.731 us; speedup 1.0000x reference)
//
#include <hip/hip_runtime.h>
#include <hip/hip_cooperative_groups.h>
#include <hip/hip_bf16.h>
#include <math.h>

namespace cg = cooperative_groups;

// Problem config (fixed)
#define BB 32      // batch
#define TT 128     // time steps
#define UU 1024    // units
#define MM 8       // memory slots
#define LL 9       // M+1
#define RR 17      // 2M+1
#define NBLK 360   // coop blocks (512 thr each; <=2 blocks/CU)

typedef __bf16 bf16x8 __attribute__((ext_vector_type(8)));
typedef float f32x4 __attribute__((ext_vector_type(4)));
typedef float f32x8 __attribute__((ext_vector_type(8)));

// exact 3-way bf16 split: v = x1 + x2 + x3 + O(2^-27 v)
__device__ __forceinline__ void split3(float v, __bf16* x1, __bf16* x2, __bf16* x3)
{
    __bf16 h1 = (__bf16)v;  float r = v - (float)h1;
    __bf16 h2 = (__bf16)r;  r -= (float)h2;
    *x1 = h1; *x2 = h2; *x3 = (__bf16)r;
}

__device__ __forceinline__ void split8(const f32x8 v, bf16x8& a, bf16x8& b, bf16x8& c)
{
#pragma unroll
    for (int j = 0; j < 8; ++j) {
        float f = v[j];
        __bf16 h1 = (__bf16)f; float r = f - (float)h1;
        __bf16 h2 = (__bf16)r; r -= (float)h2;
        a[j] = h1; b[j] = h2; c[j] = (__bf16)r;
    }
}

// ---- one 16-row x CG*16-col wave tile of split-6 MFMA GEMM, A fp32 [*,1024] ----
template<int CG>
__device__ __forceinline__ void tile6(
    const float* __restrict__ A,
    const __bf16* __restrict__ B1, const __bf16* __restrict__ B2,
    const __bf16* __restrict__ B3,
    const float* __restrict__ bias, float* __restrict__ C,
    int ldc, int act, int row0, int col0, int lane)
{
    int lr = lane & 15, kofs = (lane >> 4) * 8;
    const float* Ap = A + (size_t)(row0 + lr) * 1024 + kofs;
    size_t boff = (size_t)(col0 + lr) * 1024 + kofs;
    f32x4 acc[CG];
#pragma unroll
    for (int c = 0; c < CG; ++c) acc[c] = (f32x4){0.f, 0.f, 0.f, 0.f};

    for (int k = 0; k < 1024; k += 32) {
        f32x8 af = *(const f32x8*)(Ap + k);
        bf16x8 a1, a2, a3;
        split8(af, a1, a2, a3);
#pragma unroll
        for (int c = 0; c < CG; ++c) {
            size_t o = boff + (size_t)c * 16 * 1024 + k;
            bf16x8 b1 = *(const bf16x8*)(B1 + o);
            bf16x8 b2 = *(const bf16x8*)(B2 + o);
            bf16x8 b3 = *(const bf16x8*)(B3 + o);
            acc[c] = __builtin_amdgcn_mfma_f32_16x16x32_bf16(a1, b1, acc[c], 0, 0, 0);
            acc[c] = __builtin_amdgcn_mfma_f32_16x16x32_bf16(a1, b2, acc[c], 0, 0, 0);
            acc[c] = __builtin_amdgcn_mfma_f32_16x16x32_bf16(a2, b1, acc[c], 0, 0, 0);
            acc[c] = __builtin_amdgcn_mfma_f32_16x16x32_bf16(a1, b3, acc[c], 0, 0, 0);
            acc[c] = __builtin_amdgcn_mfma_f32_16x16x32_bf16(a2, b2, acc[c], 0, 0, 0);
            acc[c] = __builtin_amdgcn_mfma_f32_16x16x32_bf16(a3, b1, acc[c], 0, 0, 0);
        }
    }

    int r0 = row0 + (lane >> 4) * 4;
#pragma unroll
    for (int c = 0; c < CG; ++c) {
        int col = col0 + c * 16 + lr;
        float bv = bias ? bias[col] : 0.f;
#pragma unroll
        for (int r = 0; r < 4; ++r) {
            float v = acc[c][r] + bv;
            if (act == 1) {  // gelu (tanh approx, JAX default)
                float x = v;
                float t = tanhf(0.7978845608028654f * (x + 0.044715f * x * x * x));
                v = 0.5f * x * (1.f + t);
            }
            C[(size_t)(r0 + r) * ldc + col] = v;
        }
    }
}

// standalone split6 GEMM (prep only): grid (N/128, M/32), block 256
__global__ __launch_bounds__(256) void gemm6(
    const float* __restrict__ A,
    const __bf16* __restrict__ B1, const __bf16* __restrict__ B2,
    const __bf16* __restrict__ B3,
    const float* __restrict__ bias, float* __restrict__ C, int ldc, int act)
{
    int wave = threadIdx.x >> 6, lane = threadIdx.x & 63;
    int row0 = blockIdx.y * 32 + (wave >> 1) * 16;
    int col0 = blockIdx.x * 128 + (wave & 1) * 64;
    tile6<4>(A, B1, B2, B3, bias, C, ldc, act, row0, col0, lane);
}

// ---------- weight transpose + 3-way split: out[N,1024] planes = in[1024,N]^T
__global__ __launch_bounds__(256) void transpose_split(
    const float* __restrict__ in,
    __bf16* __restrict__ o1, __bf16* __restrict__ o2, __bf16* __restrict__ o3,
    int N)
{
    __shared__ float t[32][33];
    int tx = threadIdx.x & 31, ty = threadIdx.x >> 5;
    int k0 = blockIdx.y * 32, n0 = blockIdx.x * 32;
#pragma unroll
    for (int i = 0; i < 4; ++i)
        t[ty + i * 8][tx] = in[(size_t)(k0 + ty + i * 8) * N + n0 + tx];
    __syncthreads();
#pragma unroll
    for (int i = 0; i < 4; ++i) {
        float v = t[tx][ty + i * 8];
        size_t off = (size_t)(n0 + ty + i * 8) * 1024 + k0 + tx;
        split3(v, o1 + off, o2 + off, o3 + off);
    }
}

// ---------------- tiny fp32 GEMM (one-time rproj) ----------------
#define BKK 16
__global__ __launch_bounds__(256) void gemm_f32(
    const float* __restrict__ A, const float* __restrict__ B,
    float* __restrict__ C, int M, int N, int K)
{
    __shared__ float As[BKK][65];
    __shared__ float Bs[BKK][64];
    int tid = threadIdx.x;
    int row0 = blockIdx.y * 64, col0 = blockIdx.x * 64;
    int ty = tid >> 4, tx = tid & 15;
    float acc[4][4];
#pragma unroll
    for (int i = 0; i < 4; ++i)
#pragma unroll
        for (int j = 0; j < 4; ++j) acc[i][j] = 0.f;
    for (int k0 = 0; k0 < K; k0 += BKK) {
        {
            int r = tid >> 2, kv = (tid & 3) * 4;
            float4 v = make_float4(0.f, 0.f, 0.f, 0.f);
            int gr = row0 + r;
            if (gr < M) v = *(const float4*)(A + (size_t)gr * K + k0 + kv);
            As[kv + 0][r] = v.x; As[kv + 1][r] = v.y;
            As[kv + 2][r] = v.z; As[kv + 3][r] = v.w;
        }
        {
            int r = tid >> 4, cv = (tid & 15) * 4;
            float4 v = *(const float4*)(B + (size_t)(k0 + r) * N + col0 + cv);
            *(float4*)&Bs[r][cv] = v;
        }
        __syncthreads();
#pragma unroll
        for (int kk = 0; kk < BKK; ++kk) {
            float a[4], b[4];
#pragma unroll
            for (int j = 0; j < 4; ++j) a[j] = As[kk][ty * 4 + j];
#pragma unroll
            for (int j = 0; j < 4; ++j) b[j] = Bs[kk][tx * 4 + j];
#pragma unroll
            for (int i = 0; i < 4; ++i)
#pragma unroll
                for (int j = 0; j < 4; ++j) acc[i][j] += a[i] * b[j];
        }
        __syncthreads();
    }
#pragma unroll
    for (int i = 0; i < 4; ++i) {
        int gr = row0 + ty * 4 + i;
        if (gr >= M) continue;
#pragma unroll
        for (int j = 0; j < 4; ++j)
            C[(size_t)gr * N + col0 + tx * 4 + j] = acc[i][j];
    }
}

// ---------------- relative embedding table ----------------
__global__ void relemb_kernel(float* __restrict__ tab)
{
    int p = blockIdx.x;
    float pv = (float)(p - MM);
    for (int i = threadIdx.x; i < UU; i += blockDim.x) {
        float expo = (float)(i & ~1) * (1.0f / (float)UU);
        float scale = exp2f(-expo * 13.287712379549449f);  // 10000^-expo
        float ang = pv * scale;
        tab[p * UU + i] = (i & 1) ? cosf(ang) : sinf(ang);
    }
}

// ---------------- init mp ----------------
__global__ void init_mp(const float* __restrict__ xp_all, float* __restrict__ mp)
{
    int row = blockIdx.x;                 // 0..287
    int b = row / LL, l = row % LL;
    for (int u = threadIdx.x; u < UU; u += blockDim.x)
        mp[(size_t)row * UU + u] = (l == MM) ? xp_all[((size_t)b * TT) * UU + u] : 0.f;
}

// ================= shared phase bodies (coop kernel AND fallback) ============
struct ScanArgs {
    const float* xp_all;   // [4096,1024]
    const float* gx_all;   // [4096,2048]
    const float* rproj;    // [17,1024]
    const float* b1;       // [5120]
    const float* bm;       // [2048]
    const float* gam;      // [2048]
    const float* bet;      // [2048]
    const __bf16 *W1a, *W1b, *W1c;   // [5120,1024]
    const __bf16 *Wma, *Wmb, *Wmc;   // [2048,1024]
    float* mp;     // [288,1024]
    float* qkvg;   // [288,5120]
    float* a1;     // [288,1024]
    float* hbuf;   // [288,1024]
    float* m2;     // [288,1024]
    float* out;    // [32,128,1024]
};

// phase A: qkvg = mp @ [Wa|Wr] + b1. 360 blocks x 512 thr, XCD-affine map:
// bid = (colT&7) + 8*(rowT + 9*(colT>>3))  -> bid%8 == colT%8 (same-strip
// row-tiles share an XCD -> W1 strip stays L2-resident).
__device__ __forceinline__ void phaseA_body(const ScanArgs& a, int bid,
                                            int wave, int lane)
{
    int s = bid >> 3, q = bid & 7;
    int rowT = s % 9, colT = q + 8 * (s / 9);
    int row0 = rowT * 32 + (wave & 1) * 16;
    int col0 = colT * 128 + (wave >> 1) * 32;
    tile6<2>(a.mp, a.W1a, a.W1b, a.W1c, a.b1, a.qkvg, 5120, 0, row0, col0, lane);
}

// phase D/E: MLP GEMMs. 72 blocks; bid = colT + 8*rowT -> bid%8 == colT.
__device__ __forceinline__ void mlp_body(const ScanArgs& a, int bid,
                                         int wave, int lane, int which)
{
    int rowT = bid >> 3, colT = bid & 7;
    int row0 = rowT * 32 + (wave & 1) * 16;
    int col0 = colT * 128 + (wave >> 1) * 32;
    if (which == 0)
        tile6<2>(a.a1, a.Wma, a.Wmb, a.Wmc, a.bm, a.hbuf, UU, 1,
                 row0, col0, lane);
    else
        tile6<2>(a.hbuf, a.Wma + (size_t)1024 * 1024, a.Wmb + (size_t)1024 * 1024,
                 a.Wmc + (size_t)1024 * 1024, a.bm + 1024, a.m2, UU, 0,
                 row0, col0, lane);
}

// phase B: attention + LN1 for batch b. 512 threads (8 waves x 2 heads).
__device__ __forceinline__ void attn_body(const ScanArgs& a, int b, int tid,
                                          float (*sA)[UU], float* red)
{
    int wave = tid >> 6, lane = tid & 63;
    for (int hh = 0; hh < 2; ++hh) {
        int hd = wave + hh * 8;
        const float* base = a.qkvg + (size_t)b * LL * 5120 + hd * 64 + lane;
        float q[LL], k[LL], v[LL], r[RR];
#pragma unroll
        for (int l = 0; l < LL; ++l) {
            q[l] = base[l * 5120];
            k[l] = base[l * 5120 + 1024];
            v[l] = base[l * 5120 + 2048];
        }
#pragma unroll
        for (int rp = 0; rp < RR; ++rp)
            r[rp] = a.rproj[rp * UU + hd * 64 + lane];
#pragma unroll
        for (int qr = 0; qr < LL; ++qr) {
            float sc[LL];
#pragma unroll
            for (int kr = 0; kr < LL; ++kr) {
                float prod = q[qr] * (k[kr] + r[qr - kr + MM]);
#pragma unroll
                for (int o = 32; o > 0; o >>= 1) prod += __shfl_xor(prod, o);
                sc[kr] = prod * 0.125f;
            }
            float m = sc[0];
#pragma unroll
            for (int kr = 1; kr < LL; ++kr) m = fmaxf(m, sc[kr]);
            float s = 0.f;
#pragma unroll
            for (int kr = 0; kr < LL; ++kr) { sc[kr] = expf(sc[kr] - m); s += sc[kr]; }
            float inv = 1.0f / s;
            float acc = 0.f;
#pragma unroll
            for (int kr = 0; kr < LL; ++kr) acc += sc[kr] * v[kr];
            sA[qr][hd * 64 + lane] = acc * inv;
        }
    }
    __syncthreads();
    for (int l = 0; l < LL; ++l) {
        size_t row = (size_t)(b * LL + l);
        float x[2];
        float s = 0.f, ss = 0.f;
#pragma unroll
        for (int j = 0; j < 2; ++j) {
            int u = tid + j * 512;
            x[j] = a.mp[row * UU + u] + sA[l][u];
            s += x[j]; ss += x[j] * x[j];
        }
#pragma unroll
        for (int o = 32; o > 0; o >>= 1) { s += __shfl_xor(s, o); ss += __shfl_xor(ss, o); }
        if (lane == 0) { red[wave * 2] = s; red[wave * 2 + 1] = ss; }
        __syncthreads();
        float S = 0.f, SS = 0.f;
#pragma unroll
        for (int w = 0; w < 8; ++w) { S += red[w * 2]; SS += red[w * 2 + 1]; }
        __syncthreads();
        float mean = S * (1.0f / UU);
        float var = SS * (1.0f / UU) - mean * mean;
        float rstd = rsqrtf(var + 1e-6f);
#pragma unroll
        for (int j = 0; j < 2; ++j) {
            int u = tid + j * 512;
            a.a1[row * UU + u] = (x[j] - mean) * rstd * a.gam[u] + a.bet[u];
        }
    }
}

// phase F: LN2 + gates + memory update + output for one row. 512 threads.
__device__ __forceinline__ void finalize_body(const ScanArgs& a, int row, int t,
                                              int tid, float* red)
{
    int b = row / LL, l = row % LL;
    int wave = tid >> 6, lane = tid & 63;
    float x[2];
    float s = 0.f, ss = 0.f;
#pragma unroll
    for (int j = 0; j < 2; ++j) {
        int u = tid + j * 512;
        x[j] = a.a1[(size_t)row * UU + u] + a.m2[(size_t)row * UU + u];
        s += x[j]; ss += x[j] * x[j];
    }
#pragma unroll
    for (int o = 32; o > 0; o >>= 1) { s += __shfl_xor(s, o); ss += __shfl_xor(ss, o); }
    if (lane == 0) { red[wave * 2] = s; red[wave * 2 + 1] = ss; }
    __syncthreads();
    float S = 0.f, SS = 0.f;
#pragma unroll
    for (int w = 0; w < 8; ++w) { S += red[w * 2]; SS += red[w * 2 + 1]; }
    __syncthreads();
    float mean = S * (1.0f / UU);
    float rstd = rsqrtf(SS * (1.0f / UU) - mean * mean + 1e-6f);

    size_t gxoff = ((size_t)b * TT + t) * 2048;
    size_t grow = (size_t)row * 5120 + 3072;
#pragma unroll
    for (int j = 0; j < 2; ++j) {
        int u = tid + j * 512;
        float cand = (x[j] - mean) * rstd * a.gam[1024 + u] + a.bet[1024 + u];
        float tc = tanhf(cand);
        float gi = a.gx_all[gxoff + u]        + a.qkvg[grow + u];
        float gf = a.gx_all[gxoff + 1024 + u] + a.qkvg[grow + 1024 + u];
        float ig = fminf(fmaxf(0.2f * gi + 0.5f, 0.f), 1.f);
        float fg = fminf(fmaxf(0.2f * (gf + 1.0f) + 0.5f, 0.f), 1.f);
        size_t off = (size_t)row * UU + u;
        float nmp = fg * a.mp[off] + ig * tc;
        if (l < MM) {
            a.mp[off] = nmp;
        } else {
            a.out[((size_t)b * TT + t) * UU + u] = nmp;
            if (t + 1 < TT)
                a.mp[off] = a.xp_all[((size_t)b * TT + t + 1) * UU + u];
        }
    }
}

// ---------------- persistent cooperative scan kernel ----------------
__global__ __launch_bounds__(512, 4) void scan_kernel(ScanArgs a)
{
    cg::grid_group grid = cg::this_grid();
    int bid = blockIdx.x;
    int tid = threadIdx.x, wave = tid >> 6, lane = tid & 63;
    __shared__ float sA[LL][UU];
    __shared__ float red[16];

    for (int t = 0; t < TT; ++t) {
        if (bid < 360) phaseA_body(a, bid, wave, lane);
        grid.sync();
        if (bid < BB) attn_body(a, bid, tid, sA, red);
        grid.sync();
        if (bid < 72) mlp_body(a, bid, wave, lane, 0);
        grid.sync();
        if (bid < 72) mlp_body(a, bid, wave, lane, 1);
        grid.sync();
        if (bid < BB * LL) finalize_body(a, bid, t, tid, red);
        grid.sync();
    }
}

// ---------------- fallback per-phase kernels (identical numerics) ----------
__global__ __launch_bounds__(512, 4) void phaseA_k(ScanArgs a)
{
    phaseA_body(a, blockIdx.x, threadIdx.x >> 6, threadIdx.x & 63);
}
__global__ __launch_bounds__(512, 4) void attn_k(ScanArgs a)
{
    __shared__ float sA[LL][UU];
    __shared__ float red[16];
    attn_body(a, blockIdx.x, threadIdx.x, sA, red);
}
__global__ __launch_bounds__(512, 4) void mlp_k(ScanArgs a, int which)
{
    mlp_body(a, blockIdx.x, threadIdx.x >> 6, threadIdx.x & 63, which);
}
__global__ __launch_bounds__(512, 4) void finalize_k(ScanArgs a, int t)
{
    __shared__ float red[16];
    finalize_body(a, blockIdx.x, t, threadIdx.x, red);
}

// ---------------- host launcher ----------------
extern "C" void kernel_launch(void* const* d_in, const int* in_sizes, int n_in,
                              void* d_out, int out_size, void* d_ws, size_t ws_size,
                              hipStream_t stream)
{
    const float* x    = (const float*)d_in[0];
    const float* Wi   = (const float*)d_in[1];
    const float* bi   = (const float*)d_in[2];
    const float* Wg   = (const float*)d_in[3];
    const float* Wr   = (const float*)d_in[4];
    const float* br   = (const float*)d_in[5];
    const float* Wa   = (const float*)d_in[6];
    const float* ba   = (const float*)d_in[7];
    const float* Wm   = (const float*)d_in[8];
    const float* bm   = (const float*)d_in[9];
    const float* gam  = (const float*)d_in[10];
    const float* bet  = (const float*)d_in[11];
    const float* Wrel = (const float*)d_in[12];
    float* out = (float*)d_out;

    // ---- workspace layout ----
    char* w = (char*)d_ws;
    float*  xp_all = (float*)w;  w += (size_t)BB*TT*UU*4;
    float*  gx_all = (float*)w;  w += (size_t)BB*TT*2048*4;
    size_t W1N = (size_t)5120 * 1024, WMN = (size_t)2048 * 1024;
    __bf16* W1a = (__bf16*)w;    w += W1N*2;
    __bf16* W1b = (__bf16*)w;    w += W1N*2;
    __bf16* W1c = (__bf16*)w;    w += W1N*2;
    __bf16* Wma = (__bf16*)w;    w += WMN*2;
    __bf16* Wmb = (__bf16*)w;    w += WMN*2;
    __bf16* Wmc = (__bf16*)w;    w += WMN*2;
    float*  b1    = (float*)w;   w += 5120*4;
    float*  tab   = (float*)w;   w += RR*UU*4;
    float*  rproj = (float*)w;   w += RR*UU*4;
    float*  mp    = (float*)w;   w += (size_t)BB*LL*UU*4;
    // scan scratch (aliased by prep-only Wi/Wg planes)
    char* sbase = w;
    float*  qkvg  = (float*)w;   w += (size_t)BB*LL*5120*4;
    float*  a1    = (float*)w;   w += (size_t)BB*LL*UU*4;
    float*  hbuf  = (float*)w;   w += (size_t)BB*LL*UU*4;
    float*  m2    = (float*)w;   w += (size_t)BB*LL*UU*4;
    __bf16* Wia = (__bf16*)sbase;
    __bf16* Wib = Wia + (size_t)1024 * 1024;
    __bf16* Wic = Wib + (size_t)1024 * 1024;
    __bf16* Wga = Wic + (size_t)1024 * 1024;
    __bf16* Wgb = Wga + (size_t)2048 * 1024;
    __bf16* Wgc = Wgb + (size_t)2048 * 1024;

    // ---- one-time prep ----
    relemb_kernel<<<RR, 256, 0, stream>>>(tab);
    gemm_f32<<<dim3(UU / 64, 1), 256, 0, stream>>>(tab, Wrel, rproj, RR, UU, UU);
    transpose_split<<<dim3(3072 / 32, 32), 256, 0, stream>>>(Wa, W1a, W1b, W1c, 3072);
    transpose_split<<<dim3(2048 / 32, 32), 256, 0, stream>>>(
        Wr, W1a + (size_t)3072 * 1024, W1b + (size_t)3072 * 1024,
        W1c + (size_t)3072 * 1024, 2048);
    transpose_split<<<dim3(2048 / 32, 32), 256, 0, stream>>>(Wm, Wma, Wmb, Wmc, 2048);
    transpose_split<<<dim3(1024 / 32, 32), 256, 0, stream>>>(Wi, Wia, Wib, Wic, 1024);
    transpose_split<<<dim3(2048 / 32, 32), 256, 0, stream>>>(Wg, Wga, Wgb, Wgc, 2048);
    hipMemcpyAsync(b1, ba, 3072 * sizeof(float), hipMemcpyDeviceToDevice, stream);
    hipMemcpyAsync(b1 + 3072, br, 2048 * sizeof(float), hipMemcpyDeviceToDevice, stream);
    gemm6<<<dim3(UU / 128, (BB * TT) / 32), 256, 0, stream>>>(
        x, Wia, Wib, Wic, bi, xp_all, UU, 0);
    gemm6<<<dim3(2048 / 128, (BB * TT) / 32), 256, 0, stream>>>(
        x, Wga, Wgb, Wgc, nullptr, gx_all, 2048, 0);
    init_mp<<<BB * LL, 256, 0, stream>>>(xp_all, mp);

    // ---- scan ----
    ScanArgs sa;
    sa.xp_all = xp_all; sa.gx_all = gx_all; sa.rproj = rproj; sa.b1 = b1;
    sa.bm = bm; sa.gam = gam; sa.bet = bet;
    sa.W1a = W1a; sa.W1b = W1b; sa.W1c = W1c;
    sa.Wma = Wma; sa.Wmb = Wmb; sa.Wmc = Wmc;
    sa.mp = mp; sa.qkvg = qkvg; sa.a1 = a1; sa.hbuf = hbuf; sa.m2 = m2;
    sa.out = out;
    void* kargs[] = { (void*)&sa };
    hipError_t ce = hipLaunchCooperativeKernel((void*)scan_kernel, dim3(NBLK),
                                               dim3(512), kargs, 0, stream);
    if (ce != hipSuccess) {
        // fallback: same phases as separate dispatches (identical numerics)
        for (int t = 0; t < TT; ++t) {
            phaseA_k<<<360, 512, 0, stream>>>(sa);
            attn_k<<<BB, 512, 0, stream>>>(sa);
            mlp_k<<<72, 512, 0, stream>>>(sa, 0);
            mlp_k<<<72, 512, 0, stream>>>(sa, 1);
            finalize_k<<<BB * LL, 512, 0, stream>>>(sa, t);
        }
    }
}

// Round 8
// 37092.480 us; speedup vs baseline: 1.7615x; 1.7615x over previous
//
#include <hip/hip_runtime.h>
#include <hip/hip_bf16.h>
#include <math.h>

// Problem config (fixed)
#define BB 32      // batch
#define TT 128     // time steps
#define UU 1024    // units
#define MM 8       // memory slots
#define LL 9       // M+1
#define RR 17      // 2M+1

typedef __bf16 bf16x8 __attribute__((ext_vector_type(8)));
typedef float f32x4 __attribute__((ext_vector_type(4)));
typedef float f32x8 __attribute__((ext_vector_type(8)));

// exact 3-way bf16 split: v = x1 + x2 + x3 + O(2^-27 v)
__device__ __forceinline__ void split3(float v, __bf16* x1, __bf16* x2, __bf16* x3)
{
    __bf16 h1 = (__bf16)v;  float r = v - (float)h1;
    __bf16 h2 = (__bf16)r;  r -= (float)h2;
    *x1 = h1; *x2 = h2; *x3 = (__bf16)r;
}

__device__ __forceinline__ void split8(const f32x8 v, bf16x8& a, bf16x8& b, bf16x8& c)
{
#pragma unroll
    for (int j = 0; j < 8; ++j) {
        float f = v[j];
        __bf16 h1 = (__bf16)f; float r = f - (float)h1;
        __bf16 h2 = (__bf16)r; r -= (float)h2;
        a[j] = h1; b[j] = h2; c[j] = (__bf16)r;
    }
}

typedef const __attribute__((address_space(1))) void* gas1_t;
typedef __attribute__((address_space(3))) void* las3_t;
__device__ __forceinline__ void gload_lds16(const void* g, void* l)
{
    // dest = wave-uniform lds base + lane*16 (hardware semantics)
    __builtin_amdgcn_global_load_lds((gas1_t)g, (las3_t)l, 16, 0, 0);
}

// swizzle: XOR the 16B-granule bits of the within-col offset with a col hash
__device__ __forceinline__ int swz(int col) {
    return (((col & 3) ^ ((col >> 2) & 3)) << 4);
}

// ================= LDS-staged split-6 MFMA GEMM =================
// C[M,N] = A[M,1024] @ Bt[N,1024]^T (+bias,+act). A fp32 (split in-register),
// B as 3 bf16 planes. Block: 512 thr computes 32 rows x 128 cols.
// B staged to LDS per KC=32 chunk via global_load_lds (double-buffered 48KB).
// affin=1: 360-block XCD-affine map (colT%8 == bid%8). else colT=bid%ncolT.
__global__ __launch_bounds__(512) void gemm6_lds(
    const float* __restrict__ A,
    const __bf16* __restrict__ B1, const __bf16* __restrict__ B2,
    const __bf16* __restrict__ B3,
    const float* __restrict__ bias, float* __restrict__ C,
    int ldc, int act, int ncolT, int affin)
{
    __shared__ __align__(16) char Bs[2][24576];  // 2 x (3 planes x 128 col x 32 k bf16)
    int tid = threadIdx.x, wave = tid >> 6, lane = tid & 63;
    int bid = blockIdx.x;
    int rowT, colT;
    if (affin) { int q = bid & 7, s = bid >> 3; rowT = s / 5; colT = q + 8 * (s % 5); }
    else       { colT = bid % ncolT; rowT = bid / ncolT; }
    int row0 = rowT * 32, col0 = colT * 128;
    int lr = lane & 15, kg = lane >> 4;

    const float* Ap = A + (size_t)(row0 + (wave & 1) * 16 + lr) * 1024 + kg * 8;
    const __bf16* Bp0 = B1; const __bf16* Bp1 = B2; const __bf16* Bp2 = B3;

    f32x4 acc[2] = {};

    // stage chunk k0 into buffer bb; wave stages bytes [wave*3072, +3072)
    auto stage = [&](int k0, int bb) {
#pragma unroll
        for (int j = 0; j < 3; ++j) {
            int d = wave * 3072 + j * 1024 + lane * 16;  // dest byte (incl lane)
            int p = d >> 13;                 // plane
            int r = d & 8191;
            int col = r >> 6;                // 0..127
            int within = r & 63;             // multiple of 16
            int sw = within ^ swz(col);      // inverse-swizzled source offset
            const __bf16* plane = (p == 0) ? Bp0 : ((p == 1) ? Bp1 : Bp2);
            const __bf16* gp = plane + (size_t)(col0 + col) * 1024 + k0 + (sw >> 1);
            gload_lds16(gp, &Bs[bb][wave * 3072 + j * 1024]);
        }
    };

    stage(0, 0);
    __syncthreads();

    for (int ch = 0; ch < 32; ++ch) {
        int bb = ch & 1;
        if (ch + 1 < 32) stage((ch + 1) * 32, bb ^ 1);

        f32x8 af = *(const f32x8*)(Ap + ch * 32);
        bf16x8 a1, a2, a3;
        split8(af, a1, a2, a3);
#pragma unroll
        for (int c = 0; c < 2; ++c) {
            int cl = (wave >> 1) * 32 + c * 16 + lr;       // local col 0..127
            int byte = cl * 64 + ((kg * 16) ^ swz(cl));
            const char* base = &Bs[bb][0];
            bf16x8 b1 = *(const bf16x8*)(base + byte);
            bf16x8 b2 = *(const bf16x8*)(base + 8192 + byte);
            bf16x8 b3 = *(const bf16x8*)(base + 16384 + byte);
            acc[c] = __builtin_amdgcn_mfma_f32_16x16x32_bf16(a1, b1, acc[c], 0, 0, 0);
            acc[c] = __builtin_amdgcn_mfma_f32_16x16x32_bf16(a1, b2, acc[c], 0, 0, 0);
            acc[c] = __builtin_amdgcn_mfma_f32_16x16x32_bf16(a2, b1, acc[c], 0, 0, 0);
            acc[c] = __builtin_amdgcn_mfma_f32_16x16x32_bf16(a1, b3, acc[c], 0, 0, 0);
            acc[c] = __builtin_amdgcn_mfma_f32_16x16x32_bf16(a2, b2, acc[c], 0, 0, 0);
            acc[c] = __builtin_amdgcn_mfma_f32_16x16x32_bf16(a3, b1, acc[c], 0, 0, 0);
        }
        __syncthreads();   // drains stage vmcnt + protects Bs[bb] reuse
    }

    int r0 = row0 + (wave & 1) * 16 + kg * 4;
#pragma unroll
    for (int c = 0; c < 2; ++c) {
        int col = col0 + (wave >> 1) * 32 + c * 16 + lr;
        float bv = bias ? bias[col] : 0.f;
#pragma unroll
        for (int r = 0; r < 4; ++r) {
            float v = acc[c][r] + bv;
            if (act == 1) {  // gelu (tanh approx, JAX default)
                float x = v;
                float t = tanhf(0.7978845608028654f * (x + 0.044715f * x * x * x));
                v = 0.5f * x * (1.f + t);
            }
            C[(size_t)(r0 + r) * ldc + col] = v;
        }
    }
}

// ---------- weight transpose + 3-way split: out[N,1024] planes = in[1024,N]^T
__global__ __launch_bounds__(256) void transpose_split(
    const float* __restrict__ in,
    __bf16* __restrict__ o1, __bf16* __restrict__ o2, __bf16* __restrict__ o3,
    int N)
{
    __shared__ float t[32][33];
    int tx = threadIdx.x & 31, ty = threadIdx.x >> 5;
    int k0 = blockIdx.y * 32, n0 = blockIdx.x * 32;
#pragma unroll
    for (int i = 0; i < 4; ++i)
        t[ty + i * 8][tx] = in[(size_t)(k0 + ty + i * 8) * N + n0 + tx];
    __syncthreads();
#pragma unroll
    for (int i = 0; i < 4; ++i) {
        float v = t[tx][ty + i * 8];
        size_t off = (size_t)(n0 + ty + i * 8) * 1024 + k0 + tx;
        split3(v, o1 + off, o2 + off, o3 + off);
    }
}

// ---------------- tiny fp32 GEMM (one-time rproj) ----------------
#define BKK 16
__global__ __launch_bounds__(256) void gemm_f32(
    const float* __restrict__ A, const float* __restrict__ B,
    float* __restrict__ C, int M, int N, int K)
{
    __shared__ float As[BKK][65];
    __shared__ float Bs[BKK][64];
    int tid = threadIdx.x;
    int row0 = blockIdx.y * 64, col0 = blockIdx.x * 64;
    int ty = tid >> 4, tx = tid & 15;
    float acc[4][4];
#pragma unroll
    for (int i = 0; i < 4; ++i)
#pragma unroll
        for (int j = 0; j < 4; ++j) acc[i][j] = 0.f;
    for (int k0 = 0; k0 < K; k0 += BKK) {
        {
            int r = tid >> 2, kv = (tid & 3) * 4;
            float4 v = make_float4(0.f, 0.f, 0.f, 0.f);
            int gr = row0 + r;
            if (gr < M) v = *(const float4*)(A + (size_t)gr * K + k0 + kv);
            As[kv + 0][r] = v.x; As[kv + 1][r] = v.y;
            As[kv + 2][r] = v.z; As[kv + 3][r] = v.w;
        }
        {
            int r = tid >> 4, cv = (tid & 15) * 4;
            float4 v = *(const float4*)(B + (size_t)(k0 + r) * N + col0 + cv);
            *(float4*)&Bs[r][cv] = v;
        }
        __syncthreads();
#pragma unroll
        for (int kk = 0; kk < BKK; ++kk) {
            float a[4], b[4];
#pragma unroll
            for (int j = 0; j < 4; ++j) a[j] = As[kk][ty * 4 + j];
#pragma unroll
            for (int j = 0; j < 4; ++j) b[j] = Bs[kk][tx * 4 + j];
#pragma unroll
            for (int i = 0; i < 4; ++i)
#pragma unroll
                for (int j = 0; j < 4; ++j) acc[i][j] += a[i] * b[j];
        }
        __syncthreads();
    }
#pragma unroll
    for (int i = 0; i < 4; ++i) {
        int gr = row0 + ty * 4 + i;
        if (gr >= M) continue;
#pragma unroll
        for (int j = 0; j < 4; ++j)
            C[(size_t)gr * N + col0 + tx * 4 + j] = acc[i][j];
    }
}

// ---------------- relative embedding table ----------------
__global__ void relemb_kernel(float* __restrict__ tab)
{
    int p = blockIdx.x;
    float pv = (float)(p - MM);
    for (int i = threadIdx.x; i < UU; i += blockDim.x) {
        float expo = (float)(i & ~1) * (1.0f / (float)UU);
        float scale = exp2f(-expo * 13.287712379549449f);  // 10000^-expo
        float ang = pv * scale;
        tab[p * UU + i] = (i & 1) ? cosf(ang) : sinf(ang);
    }
}

// ---------------- init mp ----------------
__global__ void init_mp(const float* __restrict__ xp_all, float* __restrict__ mp)
{
    int row = blockIdx.x;                 // 0..287
    int b = row / LL, l = row % LL;
    for (int u = threadIdx.x; u < UU; u += blockDim.x)
        mp[(size_t)row * UU + u] = (l == MM) ? xp_all[((size_t)b * TT) * UU + u] : 0.f;
}

// ---------------- attention + LN1 (one block per batch element) ----------------
__global__ __launch_bounds__(512) void attn_ln(
    const float* __restrict__ qkvg, const float* __restrict__ rproj,
    const float* __restrict__ mp,
    const float* __restrict__ gamma, const float* __restrict__ beta,
    float* __restrict__ a1)
{
    __shared__ float sA[LL][UU];
    __shared__ float red[16];
    int b = blockIdx.x;
    int tid = threadIdx.x;
    int wave = tid >> 6, lane = tid & 63;

    for (int hh = 0; hh < 2; ++hh) {
        int h = wave + hh * 8;
        const float* base = qkvg + (size_t)b * LL * 5120 + h * 64 + lane;
        float q[LL], k[LL], v[LL], r[RR];
#pragma unroll
        for (int l = 0; l < LL; ++l) {
            q[l] = base[l * 5120];
            k[l] = base[l * 5120 + 1024];
            v[l] = base[l * 5120 + 2048];
        }
#pragma unroll
        for (int rp = 0; rp < RR; ++rp) r[rp] = rproj[rp * UU + h * 64 + lane];
#pragma unroll
        for (int qr = 0; qr < LL; ++qr) {
            float sc[LL];
#pragma unroll
            for (int kr = 0; kr < LL; ++kr) {
                float prod = q[qr] * (k[kr] + r[qr - kr + MM]);
#pragma unroll
                for (int o = 32; o > 0; o >>= 1) prod += __shfl_xor(prod, o);
                sc[kr] = prod * 0.125f;
            }
            float m = sc[0];
#pragma unroll
            for (int kr = 1; kr < LL; ++kr) m = fmaxf(m, sc[kr]);
            float s = 0.f;
#pragma unroll
            for (int kr = 0; kr < LL; ++kr) { sc[kr] = expf(sc[kr] - m); s += sc[kr]; }
            float inv = 1.0f / s;
            float acc = 0.f;
#pragma unroll
            for (int kr = 0; kr < LL; ++kr) acc += sc[kr] * v[kr];
            sA[qr][h * 64 + lane] = acc * inv;
        }
    }
    __syncthreads();

    for (int l = 0; l < LL; ++l) {
        size_t row = (size_t)(b * LL + l);
        float x0 = mp[row * UU + tid] + sA[l][tid];
        float x1 = mp[row * UU + tid + 512] + sA[l][tid + 512];
        float s = x0 + x1, ss = x0 * x0 + x1 * x1;
#pragma unroll
        for (int o = 32; o > 0; o >>= 1) { s += __shfl_xor(s, o); ss += __shfl_xor(ss, o); }
        if (lane == 0) { red[wave * 2] = s; red[wave * 2 + 1] = ss; }
        __syncthreads();
        float S = 0.f, SS = 0.f;
#pragma unroll
        for (int w = 0; w < 8; ++w) { S += red[w * 2]; SS += red[w * 2 + 1]; }
        __syncthreads();
        float mean = S * (1.0f / UU);
        float var = SS * (1.0f / UU) - mean * mean;
        float rstd = rsqrtf(var + 1e-6f);
        a1[row * UU + tid]       = (x0 - mean) * rstd * gamma[tid] + beta[tid];
        a1[row * UU + tid + 512] = (x1 - mean) * rstd * gamma[tid + 512] + beta[tid + 512];
    }
}

// ---------------- finalize: LN2 + gates + memory update + output ----------------
__global__ __launch_bounds__(256) void finalize_step(
    const float* __restrict__ a1, const float* __restrict__ m2,
    const float* __restrict__ qkvg, const float* __restrict__ gx_all,
    const float* __restrict__ xp_all,
    const float* __restrict__ gamma, const float* __restrict__ beta,
    float* __restrict__ mp, float* __restrict__ out, int t)
{
    __shared__ float red[8];
    int row = blockIdx.x;                 // 0..287
    int b = row / LL, l = row % LL;
    int tid = threadIdx.x;
    int wave = tid >> 6, lane = tid & 63;

    float x[4];
    float s = 0.f, ss = 0.f;
#pragma unroll
    for (int j = 0; j < 4; ++j) {
        int u = tid + j * 256;
        x[j] = a1[(size_t)row * UU + u] + m2[(size_t)row * UU + u];
        s += x[j]; ss += x[j] * x[j];
    }
#pragma unroll
    for (int o = 32; o > 0; o >>= 1) { s += __shfl_xor(s, o); ss += __shfl_xor(ss, o); }
    if (lane == 0) { red[wave * 2] = s; red[wave * 2 + 1] = ss; }
    __syncthreads();
    float S = 0.f, SS = 0.f;
#pragma unroll
    for (int w = 0; w < 4; ++w) { S += red[w * 2]; SS += red[w * 2 + 1]; }
    float mean = S * (1.0f / UU);
    float rstd = rsqrtf(SS * (1.0f / UU) - mean * mean + 1e-6f);

    size_t gxoff = ((size_t)b * TT + t) * 2048;
    size_t grow = (size_t)row * 5120 + 3072;
#pragma unroll
    for (int j = 0; j < 4; ++j) {
        int u = tid + j * 256;
        float cand = (x[j] - mean) * rstd * gamma[1024 + u] + beta[1024 + u];
        float tc = tanhf(cand);
        float gi = gx_all[gxoff + u]        + qkvg[grow + u];
        float gf = gx_all[gxoff + 1024 + u] + qkvg[grow + 1024 + u];
        float ig = fminf(fmaxf(0.2f * gi + 0.5f, 0.f), 1.f);
        float fg = fminf(fmaxf(0.2f * (gf + 1.0f) + 0.5f, 0.f), 1.f);
        size_t off = (size_t)row * UU + u;
        float nmp = fg * mp[off] + ig * tc;
        if (l < MM) {
            mp[off] = nmp;
        } else {
            out[((size_t)b * TT + t) * UU + u] = nmp;
            if (t + 1 < TT)
                mp[off] = xp_all[((size_t)b * TT + t + 1) * UU + u];
        }
    }
}

// ---------------- host launcher ----------------
extern "C" void kernel_launch(void* const* d_in, const int* in_sizes, int n_in,
                              void* d_out, int out_size, void* d_ws, size_t ws_size,
                              hipStream_t stream)
{
    const float* x    = (const float*)d_in[0];
    const float* Wi   = (const float*)d_in[1];
    const float* bi   = (const float*)d_in[2];
    const float* Wg   = (const float*)d_in[3];
    const float* Wr   = (const float*)d_in[4];
    const float* br   = (const float*)d_in[5];
    const float* Wa   = (const float*)d_in[6];
    const float* ba   = (const float*)d_in[7];
    const float* Wm   = (const float*)d_in[8];
    const float* bm   = (const float*)d_in[9];
    const float* gam  = (const float*)d_in[10];
    const float* bet  = (const float*)d_in[11];
    const float* Wrel = (const float*)d_in[12];
    float* out = (float*)d_out;

    // ---- workspace layout ----
    char* w = (char*)d_ws;
    float*  xp_all = (float*)w;  w += (size_t)BB*TT*UU*4;        // 16.8 MB
    float*  gx_all = (float*)w;  w += (size_t)BB*TT*2048*4;      // 33.6 MB
    size_t W1N = (size_t)5120 * 1024, WMN = (size_t)2048 * 1024;
    __bf16* W1a = (__bf16*)w;    w += W1N*2;                     // 31.5 MB total
    __bf16* W1b = (__bf16*)w;    w += W1N*2;
    __bf16* W1c = (__bf16*)w;    w += W1N*2;
    __bf16* Wma = (__bf16*)w;    w += WMN*2;                     // 12.6 MB total
    __bf16* Wmb = (__bf16*)w;    w += WMN*2;
    __bf16* Wmc = (__bf16*)w;    w += WMN*2;
    float*  b1    = (float*)w;   w += 5120*4;
    float*  tab   = (float*)w;   w += RR*UU*4;
    float*  rproj = (float*)w;   w += RR*UU*4;
    float*  mp    = (float*)w;   w += (size_t)BB*LL*UU*4;
    // scan scratch (aliased by prep-only Wi/Wg planes, as in R5/R6 — proven fit)
    char* sbase = w;
    float*  qkvg  = (float*)w;   w += (size_t)BB*LL*5120*4;      // 5.9 MB
    float*  a1    = (float*)w;   w += (size_t)BB*LL*UU*4;
    float*  hbuf  = (float*)w;   w += (size_t)BB*LL*UU*4;        // fp32 now
    float*  m2    = (float*)w;   w += (size_t)BB*LL*UU*4;
    __bf16* Wia = (__bf16*)sbase;
    __bf16* Wib = Wia + (size_t)1024 * 1024;
    __bf16* Wic = Wib + (size_t)1024 * 1024;
    __bf16* Wga = Wic + (size_t)1024 * 1024;
    __bf16* Wgb = Wga + (size_t)2048 * 1024;
    __bf16* Wgc = Wgb + (size_t)2048 * 1024;

    // ---- one-time prep ----
    relemb_kernel<<<RR, 256, 0, stream>>>(tab);
    gemm_f32<<<dim3(UU / 64, 1), 256, 0, stream>>>(tab, Wrel, rproj, RR, UU, UU);
    transpose_split<<<dim3(3072 / 32, 32), 256, 0, stream>>>(Wa, W1a, W1b, W1c, 3072);
    transpose_split<<<dim3(2048 / 32, 32), 256, 0, stream>>>(
        Wr, W1a + (size_t)3072 * 1024, W1b + (size_t)3072 * 1024,
        W1c + (size_t)3072 * 1024, 2048);
    transpose_split<<<dim3(2048 / 32, 32), 256, 0, stream>>>(Wm, Wma, Wmb, Wmc, 2048);
    transpose_split<<<dim3(1024 / 32, 32), 256, 0, stream>>>(Wi, Wia, Wib, Wic, 1024);
    transpose_split<<<dim3(2048 / 32, 32), 256, 0, stream>>>(Wg, Wga, Wgb, Wgc, 2048);
    hipMemcpyAsync(b1, ba, 3072 * sizeof(float), hipMemcpyDeviceToDevice, stream);
    hipMemcpyAsync(b1 + 3072, br, 2048 * sizeof(float), hipMemcpyDeviceToDevice, stream);
    // xp_all = x @ Wi + bi ; gx_all = x @ Wg   (LDS-staged split6)
    gemm6_lds<<<8 * 128, 512, 0, stream>>>(x, Wia, Wib, Wic, bi, xp_all,
                                           1024, 0, 8, 0);
    gemm6_lds<<<16 * 128, 512, 0, stream>>>(x, Wga, Wgb, Wgc, nullptr, gx_all,
                                            2048, 0, 16, 0);
    init_mp<<<BB * LL, 256, 0, stream>>>(xp_all, mp);

    // ---- sequential scan (5 dispatches/step) ----
    for (int t = 0; t < TT; ++t) {
        // qkvg[288,5120] = mp @ [Wa|Wr] + [ba|br]
        gemm6_lds<<<360, 512, 0, stream>>>(mp, W1a, W1b, W1c, b1, qkvg,
                                           5120, 0, 40, 1);
        attn_ln<<<BB, 512, 0, stream>>>(qkvg, rproj, mp, gam, bet, a1);
        // hbuf = gelu(a1 @ Wm[:,:U] + bm[:U])
        gemm6_lds<<<72, 512, 0, stream>>>(a1, Wma, Wmb, Wmc, bm, hbuf,
                                          1024, 1, 8, 0);
        // m2 = hbuf @ Wm[:,U:] + bm[U:]
        gemm6_lds<<<72, 512, 0, stream>>>(hbuf, Wma + (size_t)1024 * 1024,
                                          Wmb + (size_t)1024 * 1024,
                                          Wmc + (size_t)1024 * 1024,
                                          bm + 1024, m2, 1024, 0, 8, 0);
        finalize_step<<<BB * LL, 256, 0, stream>>>(a1, m2, qkvg, gx_all, xp_all,
                                                   gam, bet, mp, out, t);
    }
}

// Round 9
// 25072.606 us; speedup vs baseline: 2.6059x; 1.4794x over previous
//
#include <hip/hip_runtime.h>
#include <hip/hip_bf16.h>
#include <math.h>

// Problem config (fixed)
#define BB 32      // batch
#define TT 128     // time steps
#define UU 1024    // units
#define MM 8       // memory slots
#define LL 9       // M+1
#define RR 17      // 2M+1
#define MROWS 288  // BB*LL
#define NKS 4      // K-split factor
#define KLEN 256   // K per split

typedef __bf16 bf16x8 __attribute__((ext_vector_type(8)));
typedef float f32x4 __attribute__((ext_vector_type(4)));
typedef float f32x8 __attribute__((ext_vector_type(8)));

// exact 3-way bf16 split: v = x1 + x2 + x3 + O(2^-27 v)
__device__ __forceinline__ void split3(float v, __bf16* x1, __bf16* x2, __bf16* x3)
{
    __bf16 h1 = (__bf16)v;  float r = v - (float)h1;
    __bf16 h2 = (__bf16)r;  r -= (float)h2;
    *x1 = h1; *x2 = h2; *x3 = (__bf16)r;
}

__device__ __forceinline__ void split8(const f32x8 v, bf16x8& a, bf16x8& b, bf16x8& c)
{
#pragma unroll
    for (int j = 0; j < 8; ++j) {
        float f = v[j];
        __bf16 h1 = (__bf16)f; float r = f - (float)h1;
        __bf16 h2 = (__bf16)r; r -= (float)h2;
        a[j] = h1; b[j] = h2; c[j] = (__bf16)r;
    }
}

__device__ __forceinline__ float gelu_f(float x)
{
    float t = tanhf(0.7978845608028654f * (x + 0.044715f * x * x * x));
    return 0.5f * x * (1.f + t);
}

// ================= K-split split-6 MFMA GEMM (no LDS, no barriers) ==========
// Partial[ks][MROWS][N] += A[MROWS,1024(kslice)] @ Bt[N,1024(kslice)]^T.
// Block 256 thr = 4 waves in 2x2; wave tile 16 rows x CG*16 cols.
// Block tile 32 rows x CG*32 cols. rowT in [0,9), colT in [0,ncolT), ks in [0,4).
// bid = (g&7) + 8*((g>>3) + GdivP*rowT), g = colT*NKS+ks, GdivP = ncolT*NKS/8.
// Same-g blocks (9 rowT) share one B-slice and land on one XCD (bid%8 == g%8).
template<int CG>
__global__ __launch_bounds__(256) void gemmks(
    const float* __restrict__ A,
    const __bf16* __restrict__ B1, const __bf16* __restrict__ B2,
    const __bf16* __restrict__ B3,
    float* __restrict__ P, int N, int GdivP)
{
    int tid = threadIdx.x, wave = tid >> 6, lane = tid & 63;
    int bid = blockIdx.x;
    int x = bid & 7, inner = bid >> 3;
    int q = inner % GdivP, rowT = inner / GdivP;
    int g = x + 8 * q;
    int colT = g / NKS, ks = g % NKS;

    int lr = lane & 15, kg = lane >> 4;
    int row0 = rowT * 32 + (wave & 1) * 16;
    int col0 = colT * (CG * 32) + (wave >> 1) * (CG * 16);
    int kbase = ks * KLEN;

    const float* Ap = A + (size_t)(row0 + lr) * 1024 + kbase + kg * 8;
    size_t boff = (size_t)(col0 + lr) * 1024 + kbase + kg * 8;

    f32x4 acc[CG];
#pragma unroll
    for (int c = 0; c < CG; ++c) acc[c] = (f32x4){0.f, 0.f, 0.f, 0.f};

#pragma unroll
    for (int k = 0; k < KLEN; k += 32) {
        f32x8 af = *(const f32x8*)(Ap + k);
        bf16x8 a1, a2, a3;
        split8(af, a1, a2, a3);
#pragma unroll
        for (int c = 0; c < CG; ++c) {
            size_t o = boff + (size_t)c * 16 * 1024 + k;
            bf16x8 b1 = *(const bf16x8*)(B1 + o);
            bf16x8 b2 = *(const bf16x8*)(B2 + o);
            bf16x8 b3 = *(const bf16x8*)(B3 + o);
            acc[c] = __builtin_amdgcn_mfma_f32_16x16x32_bf16(a1, b1, acc[c], 0, 0, 0);
            acc[c] = __builtin_amdgcn_mfma_f32_16x16x32_bf16(a1, b2, acc[c], 0, 0, 0);
            acc[c] = __builtin_amdgcn_mfma_f32_16x16x32_bf16(a2, b1, acc[c], 0, 0, 0);
            acc[c] = __builtin_amdgcn_mfma_f32_16x16x32_bf16(a1, b3, acc[c], 0, 0, 0);
            acc[c] = __builtin_amdgcn_mfma_f32_16x16x32_bf16(a2, b2, acc[c], 0, 0, 0);
            acc[c] = __builtin_amdgcn_mfma_f32_16x16x32_bf16(a3, b1, acc[c], 0, 0, 0);
        }
    }

    int r0 = row0 + kg * 4;
    float* Pk = P + (size_t)ks * MROWS * N;
#pragma unroll
    for (int c = 0; c < CG; ++c) {
        int col = col0 + c * 16 + lr;
#pragma unroll
        for (int r = 0; r < 4; ++r)
            Pk[(size_t)(r0 + r) * N + col] = acc[c][r];
    }
}

// combine 4 K-split partials + bias (+optional gelu): out = f(sum + bias)
__global__ __launch_bounds__(256) void add4(
    const float* __restrict__ P, const float* __restrict__ bias,
    float* __restrict__ out, int N, int act, int total4)
{
    int idx = blockIdx.x * 256 + threadIdx.x;
    if (idx >= total4) return;
    size_t e = (size_t)idx * 4;
    size_t SP = (size_t)MROWS * N;
    int col = (int)(e % N);
    f32x4 p0 = *(const f32x4*)(P + e);
    f32x4 p1 = *(const f32x4*)(P + SP + e);
    f32x4 p2 = *(const f32x4*)(P + 2 * SP + e);
    f32x4 p3 = *(const f32x4*)(P + 3 * SP + e);
    f32x4 bv = *(const f32x4*)(bias + col);
    f32x4 s;
#pragma unroll
    for (int j = 0; j < 4; ++j) {
        float v = ((p0[j] + p1[j]) + (p2[j] + p3[j])) + bv[j];
        s[j] = act ? gelu_f(v) : v;
    }
    *(f32x4*)(out + e) = s;
}

// ---- direct split6 GEMM (prep only): one 16x(CG*16) wave tile ----
template<int CG>
__device__ __forceinline__ void tile6(
    const float* __restrict__ A,
    const __bf16* __restrict__ B1, const __bf16* __restrict__ B2,
    const __bf16* __restrict__ B3,
    const float* __restrict__ bias, float* __restrict__ C,
    int ldc, int act, int row0, int col0, int lane)
{
    int lr = lane & 15, kofs = (lane >> 4) * 8;
    const float* Ap = A + (size_t)(row0 + lr) * 1024 + kofs;
    size_t boff = (size_t)(col0 + lr) * 1024 + kofs;
    f32x4 acc[CG];
#pragma unroll
    for (int c = 0; c < CG; ++c) acc[c] = (f32x4){0.f, 0.f, 0.f, 0.f};

    for (int k = 0; k < 1024; k += 32) {
        f32x8 af = *(const f32x8*)(Ap + k);
        bf16x8 a1, a2, a3;
        split8(af, a1, a2, a3);
#pragma unroll
        for (int c = 0; c < CG; ++c) {
            size_t o = boff + (size_t)c * 16 * 1024 + k;
            bf16x8 b1 = *(const bf16x8*)(B1 + o);
            bf16x8 b2 = *(const bf16x8*)(B2 + o);
            bf16x8 b3 = *(const bf16x8*)(B3 + o);
            acc[c] = __builtin_amdgcn_mfma_f32_16x16x32_bf16(a1, b1, acc[c], 0, 0, 0);
            acc[c] = __builtin_amdgcn_mfma_f32_16x16x32_bf16(a1, b2, acc[c], 0, 0, 0);
            acc[c] = __builtin_amdgcn_mfma_f32_16x16x32_bf16(a2, b1, acc[c], 0, 0, 0);
            acc[c] = __builtin_amdgcn_mfma_f32_16x16x32_bf16(a1, b3, acc[c], 0, 0, 0);
            acc[c] = __builtin_amdgcn_mfma_f32_16x16x32_bf16(a2, b2, acc[c], 0, 0, 0);
            acc[c] = __builtin_amdgcn_mfma_f32_16x16x32_bf16(a3, b1, acc[c], 0, 0, 0);
        }
    }

    int r0 = row0 + (lane >> 4) * 4;
#pragma unroll
    for (int c = 0; c < CG; ++c) {
        int col = col0 + c * 16 + lr;
        float bv = bias ? bias[col] : 0.f;
#pragma unroll
        for (int r = 0; r < 4; ++r) {
            float v = acc[c][r] + bv;
            if (act == 1) v = gelu_f(v);
            C[(size_t)(r0 + r) * ldc + col] = v;
        }
    }
}

__global__ __launch_bounds__(256) void gemm6(
    const float* __restrict__ A,
    const __bf16* __restrict__ B1, const __bf16* __restrict__ B2,
    const __bf16* __restrict__ B3,
    const float* __restrict__ bias, float* __restrict__ C, int ldc, int act)
{
    int wave = threadIdx.x >> 6, lane = threadIdx.x & 63;
    int row0 = blockIdx.y * 32 + (wave >> 1) * 16;
    int col0 = blockIdx.x * 128 + (wave & 1) * 64;
    tile6<4>(A, B1, B2, B3, bias, C, ldc, act, row0, col0, lane);
}

// ---------- weight transpose + 3-way split: out[N,1024] planes = in[1024,N]^T
__global__ __launch_bounds__(256) void transpose_split(
    const float* __restrict__ in,
    __bf16* __restrict__ o1, __bf16* __restrict__ o2, __bf16* __restrict__ o3,
    int N)
{
    __shared__ float t[32][33];
    int tx = threadIdx.x & 31, ty = threadIdx.x >> 5;
    int k0 = blockIdx.y * 32, n0 = blockIdx.x * 32;
#pragma unroll
    for (int i = 0; i < 4; ++i)
        t[ty + i * 8][tx] = in[(size_t)(k0 + ty + i * 8) * N + n0 + tx];
    __syncthreads();
#pragma unroll
    for (int i = 0; i < 4; ++i) {
        float v = t[tx][ty + i * 8];
        size_t off = (size_t)(n0 + ty + i * 8) * 1024 + k0 + tx;
        split3(v, o1 + off, o2 + off, o3 + off);
    }
}

// ---------------- tiny fp32 GEMM (one-time rproj) ----------------
#define BKK 16
__global__ __launch_bounds__(256) void gemm_f32(
    const float* __restrict__ A, const float* __restrict__ B,
    float* __restrict__ C, int M, int N, int K)
{
    __shared__ float As[BKK][65];
    __shared__ float Bs[BKK][64];
    int tid = threadIdx.x;
    int row0 = blockIdx.y * 64, col0 = blockIdx.x * 64;
    int ty = tid >> 4, tx = tid & 15;
    float acc[4][4];
#pragma unroll
    for (int i = 0; i < 4; ++i)
#pragma unroll
        for (int j = 0; j < 4; ++j) acc[i][j] = 0.f;
    for (int k0 = 0; k0 < K; k0 += BKK) {
        {
            int r = tid >> 2, kv = (tid & 3) * 4;
            float4 v = make_float4(0.f, 0.f, 0.f, 0.f);
            int gr = row0 + r;
            if (gr < M) v = *(const float4*)(A + (size_t)gr * K + k0 + kv);
            As[kv + 0][r] = v.x; As[kv + 1][r] = v.y;
            As[kv + 2][r] = v.z; As[kv + 3][r] = v.w;
        }
        {
            int r = tid >> 4, cv = (tid & 15) * 4;
            float4 v = *(const float4*)(B + (size_t)(k0 + r) * N + col0 + cv);
            *(float4*)&Bs[r][cv] = v;
        }
        __syncthreads();
#pragma unroll
        for (int kk = 0; kk < BKK; ++kk) {
            float a[4], b[4];
#pragma unroll
            for (int j = 0; j < 4; ++j) a[j] = As[kk][ty * 4 + j];
#pragma unroll
            for (int j = 0; j < 4; ++j) b[j] = Bs[kk][tx * 4 + j];
#pragma unroll
            for (int i = 0; i < 4; ++i)
#pragma unroll
                for (int j = 0; j < 4; ++j) acc[i][j] += a[i] * b[j];
        }
        __syncthreads();
    }
#pragma unroll
    for (int i = 0; i < 4; ++i) {
        int gr = row0 + ty * 4 + i;
        if (gr >= M) continue;
#pragma unroll
        for (int j = 0; j < 4; ++j)
            C[(size_t)gr * N + col0 + tx * 4 + j] = acc[i][j];
    }
}

// ---------------- relative embedding table ----------------
__global__ void relemb_kernel(float* __restrict__ tab)
{
    int p = blockIdx.x;
    float pv = (float)(p - MM);
    for (int i = threadIdx.x; i < UU; i += blockDim.x) {
        float expo = (float)(i & ~1) * (1.0f / (float)UU);
        float scale = exp2f(-expo * 13.287712379549449f);  // 10000^-expo
        float ang = pv * scale;
        tab[p * UU + i] = (i & 1) ? cosf(ang) : sinf(ang);
    }
}

// ---------------- init mp ----------------
__global__ void init_mp(const float* __restrict__ xp_all, float* __restrict__ mp)
{
    int row = blockIdx.x;                 // 0..287
    int b = row / LL, l = row % LL;
    for (int u = threadIdx.x; u < UU; u += blockDim.x)
        mp[(size_t)row * UU + u] = (l == MM) ? xp_all[((size_t)b * TT) * UU + u] : 0.f;
}

// ---------------- attention + LN1 (one block per batch element) ----------------
__global__ __launch_bounds__(512) void attn_ln(
    const float* __restrict__ qkvg, const float* __restrict__ rproj,
    const float* __restrict__ mp,
    const float* __restrict__ gamma, const float* __restrict__ beta,
    float* __restrict__ a1)
{
    __shared__ float sA[LL][UU];
    __shared__ float red[16];
    int b = blockIdx.x;
    int tid = threadIdx.x;
    int wave = tid >> 6, lane = tid & 63;

    for (int hh = 0; hh < 2; ++hh) {
        int h = wave + hh * 8;
        const float* base = qkvg + (size_t)b * LL * 5120 + h * 64 + lane;
        float q[LL], k[LL], v[LL], r[RR];
#pragma unroll
        for (int l = 0; l < LL; ++l) {
            q[l] = base[l * 5120];
            k[l] = base[l * 5120 + 1024];
            v[l] = base[l * 5120 + 2048];
        }
#pragma unroll
        for (int rp = 0; rp < RR; ++rp) r[rp] = rproj[rp * UU + h * 64 + lane];
#pragma unroll
        for (int qr = 0; qr < LL; ++qr) {
            float sc[LL];
#pragma unroll
            for (int kr = 0; kr < LL; ++kr) {
                float prod = q[qr] * (k[kr] + r[qr - kr + MM]);
#pragma unroll
                for (int o = 32; o > 0; o >>= 1) prod += __shfl_xor(prod, o);
                sc[kr] = prod * 0.125f;
            }
            float m = sc[0];
#pragma unroll
            for (int kr = 1; kr < LL; ++kr) m = fmaxf(m, sc[kr]);
            float s = 0.f;
#pragma unroll
            for (int kr = 0; kr < LL; ++kr) { sc[kr] = expf(sc[kr] - m); s += sc[kr]; }
            float inv = 1.0f / s;
            float acc = 0.f;
#pragma unroll
            for (int kr = 0; kr < LL; ++kr) acc += sc[kr] * v[kr];
            sA[qr][h * 64 + lane] = acc * inv;
        }
    }
    __syncthreads();

    for (int l = 0; l < LL; ++l) {
        size_t row = (size_t)(b * LL + l);
        float x0 = mp[row * UU + tid] + sA[l][tid];
        float x1 = mp[row * UU + tid + 512] + sA[l][tid + 512];
        float s = x0 + x1, ss = x0 * x0 + x1 * x1;
#pragma unroll
        for (int o = 32; o > 0; o >>= 1) { s += __shfl_xor(s, o); ss += __shfl_xor(ss, o); }
        if (lane == 0) { red[wave * 2] = s; red[wave * 2 + 1] = ss; }
        __syncthreads();
        float S = 0.f, SS = 0.f;
#pragma unroll
        for (int w = 0; w < 8; ++w) { S += red[w * 2]; SS += red[w * 2 + 1]; }
        __syncthreads();
        float mean = S * (1.0f / UU);
        float var = SS * (1.0f / UU) - mean * mean;
        float rstd = rsqrtf(var + 1e-6f);
        a1[row * UU + tid]       = (x0 - mean) * rstd * gamma[tid] + beta[tid];
        a1[row * UU + tid + 512] = (x1 - mean) * rstd * gamma[tid + 512] + beta[tid + 512];
    }
}

// ------- finalize: combine m2 partials + LN2 + gates + memory update --------
__global__ __launch_bounds__(256) void finalize_step(
    const float* __restrict__ a1, const float* __restrict__ m2P,
    const float* __restrict__ bm,
    const float* __restrict__ qkvg, const float* __restrict__ gx_all,
    const float* __restrict__ xp_all,
    const float* __restrict__ gamma, const float* __restrict__ beta,
    float* __restrict__ mp, float* __restrict__ out, int t)
{
    __shared__ float red[8];
    int row = blockIdx.x;                 // 0..287
    int b = row / LL, l = row % LL;
    int tid = threadIdx.x;
    int wave = tid >> 6, lane = tid & 63;
    const size_t SP = (size_t)MROWS * UU;

    float x[4];
    float s = 0.f, ss = 0.f;
#pragma unroll
    for (int j = 0; j < 4; ++j) {
        int u = tid + j * 256;
        size_t off = (size_t)row * UU + u;
        float m2v = ((m2P[off] + m2P[SP + off]) + (m2P[2 * SP + off] + m2P[3 * SP + off]))
                    + bm[1024 + u];
        x[j] = a1[off] + m2v;
        s += x[j]; ss += x[j] * x[j];
    }
#pragma unroll
    for (int o = 32; o > 0; o >>= 1) { s += __shfl_xor(s, o); ss += __shfl_xor(ss, o); }
    if (lane == 0) { red[wave * 2] = s; red[wave * 2 + 1] = ss; }
    __syncthreads();
    float S = 0.f, SS = 0.f;
#pragma unroll
    for (int w = 0; w < 4; ++w) { S += red[w * 2]; SS += red[w * 2 + 1]; }
    float mean = S * (1.0f / UU);
    float rstd = rsqrtf(SS * (1.0f / UU) - mean * mean + 1e-6f);

    size_t gxoff = ((size_t)b * TT + t) * 2048;
    size_t grow = (size_t)row * 5120 + 3072;
#pragma unroll
    for (int j = 0; j < 4; ++j) {
        int u = tid + j * 256;
        float cand = (x[j] - mean) * rstd * gamma[1024 + u] + beta[1024 + u];
        float tc = tanhf(cand);
        float gi = gx_all[gxoff + u]        + qkvg[grow + u];
        float gf = gx_all[gxoff + 1024 + u] + qkvg[grow + 1024 + u];
        float ig = fminf(fmaxf(0.2f * gi + 0.5f, 0.f), 1.f);
        float fg = fminf(fmaxf(0.2f * (gf + 1.0f) + 0.5f, 0.f), 1.f);
        size_t off = (size_t)row * UU + u;
        float nmp = fg * mp[off] + ig * tc;
        if (l < MM) {
            mp[off] = nmp;
        } else {
            out[((size_t)b * TT + t) * UU + u] = nmp;
            if (t + 1 < TT)
                mp[off] = xp_all[((size_t)b * TT + t + 1) * UU + u];
        }
    }
}

// ---------------- host launcher ----------------
extern "C" void kernel_launch(void* const* d_in, const int* in_sizes, int n_in,
                              void* d_out, int out_size, void* d_ws, size_t ws_size,
                              hipStream_t stream)
{
    const float* x    = (const float*)d_in[0];
    const float* Wi   = (const float*)d_in[1];
    const float* bi   = (const float*)d_in[2];
    const float* Wg   = (const float*)d_in[3];
    const float* Wr   = (const float*)d_in[4];
    const float* br   = (const float*)d_in[5];
    const float* Wa   = (const float*)d_in[6];
    const float* ba   = (const float*)d_in[7];
    const float* Wm   = (const float*)d_in[8];
    const float* bm   = (const float*)d_in[9];
    const float* gam  = (const float*)d_in[10];
    const float* bet  = (const float*)d_in[11];
    const float* Wrel = (const float*)d_in[12];
    float* out = (float*)d_out;

    // ---- workspace layout ----
    char* w = (char*)d_ws;
    float*  xp_all = (float*)w;  w += (size_t)BB*TT*UU*4;        // 16.8 MB
    float*  gx_all = (float*)w;  w += (size_t)BB*TT*2048*4;      // 33.6 MB
    size_t W1N = (size_t)5120 * 1024, WMN = (size_t)2048 * 1024;
    __bf16* W1a = (__bf16*)w;    w += W1N*2;                     // 31.5 MB total
    __bf16* W1b = (__bf16*)w;    w += W1N*2;
    __bf16* W1c = (__bf16*)w;    w += W1N*2;
    __bf16* Wma = (__bf16*)w;    w += WMN*2;                     // 12.6 MB total
    __bf16* Wmb = (__bf16*)w;    w += WMN*2;
    __bf16* Wmc = (__bf16*)w;    w += WMN*2;
    float*  b1    = (float*)w;   w += 5120*4;
    float*  tab   = (float*)w;   w += RR*UU*4;
    float*  rproj = (float*)w;   w += RR*UU*4;
    float*  mp    = (float*)w;   w += (size_t)MROWS*UU*4;
    float*  qkvg  = (float*)w;   w += (size_t)MROWS*5120*4;      // 5.9 MB
    float*  a1    = (float*)w;   w += (size_t)MROWS*UU*4;
    float*  hbuf  = (float*)w;   w += (size_t)MROWS*UU*4;
    // partials (qkvgP aliased by prep-only Wi/Wg planes)
    char* sbase = w;
    float*  qkvgP = (float*)w;   w += (size_t)NKS*MROWS*5120*4;  // 23.6 MB
    float*  m1P   = (float*)w;   w += (size_t)NKS*MROWS*UU*4;    // 4.7 MB
    float*  m2P   = (float*)w;   w += (size_t)NKS*MROWS*UU*4;    // 4.7 MB
    __bf16* Wia = (__bf16*)sbase;
    __bf16* Wib = Wia + (size_t)1024 * 1024;
    __bf16* Wic = Wib + (size_t)1024 * 1024;
    __bf16* Wga = Wic + (size_t)1024 * 1024;
    __bf16* Wgb = Wga + (size_t)2048 * 1024;
    __bf16* Wgc = Wgb + (size_t)2048 * 1024;   // 18.9 MB < 23.6 MB ✓

    // ---- one-time prep ----
    relemb_kernel<<<RR, 256, 0, stream>>>(tab);
    gemm_f32<<<dim3(UU / 64, 1), 256, 0, stream>>>(tab, Wrel, rproj, RR, UU, UU);
    transpose_split<<<dim3(3072 / 32, 32), 256, 0, stream>>>(Wa, W1a, W1b, W1c, 3072);
    transpose_split<<<dim3(2048 / 32, 32), 256, 0, stream>>>(
        Wr, W1a + (size_t)3072 * 1024, W1b + (size_t)3072 * 1024,
        W1c + (size_t)3072 * 1024, 2048);
    transpose_split<<<dim3(2048 / 32, 32), 256, 0, stream>>>(Wm, Wma, Wmb, Wmc, 2048);
    transpose_split<<<dim3(1024 / 32, 32), 256, 0, stream>>>(Wi, Wia, Wib, Wic, 1024);
    transpose_split<<<dim3(2048 / 32, 32), 256, 0, stream>>>(Wg, Wga, Wgb, Wgc, 2048);
    hipMemcpyAsync(b1, ba, 3072 * sizeof(float), hipMemcpyDeviceToDevice, stream);
    hipMemcpyAsync(b1 + 3072, br, 2048 * sizeof(float), hipMemcpyDeviceToDevice, stream);
    gemm6<<<dim3(UU / 128, (BB * TT) / 32), 256, 0, stream>>>(
        x, Wia, Wib, Wic, bi, xp_all, UU, 0);
    gemm6<<<dim3(2048 / 128, (BB * TT) / 32), 256, 0, stream>>>(
        x, Wga, Wgb, Wgc, nullptr, gx_all, 2048, 0);
    init_mp<<<MROWS, 256, 0, stream>>>(xp_all, mp);

    // ---- sequential scan (7 dispatches/step) ----
    // phase A: ncolT = 5120/64 = 80, GdivP = 80*4/8 = 40, blocks = 8*40*9 = 2880
    // MLPs:    ncolT = 1024/64 = 16, GdivP = 16*4/8 = 8,  blocks = 8*8*9  = 576
    for (int t = 0; t < TT; ++t) {
        gemmks<2><<<2880, 256, 0, stream>>>(mp, W1a, W1b, W1c, qkvgP, 5120, 40);
        add4<<<(MROWS * 5120 / 4 + 255) / 256, 256, 0, stream>>>(
            qkvgP, b1, qkvg, 5120, 0, MROWS * 5120 / 4);
        attn_ln<<<BB, 512, 0, stream>>>(qkvg, rproj, mp, gam, bet, a1);
        gemmks<2><<<576, 256, 0, stream>>>(a1, Wma, Wmb, Wmc, m1P, UU, 8);
        add4<<<(MROWS * UU / 4 + 255) / 256, 256, 0, stream>>>(
            m1P, bm, hbuf, UU, 1, MROWS * UU / 4);
        gemmks<2><<<576, 256, 0, stream>>>(hbuf, Wma + (size_t)1024 * 1024,
                                           Wmb + (size_t)1024 * 1024,
                                           Wmc + (size_t)1024 * 1024, m2P, UU, 8);
        finalize_step<<<MROWS, 256, 0, stream>>>(a1, m2P, bm, qkvg, gx_all, xp_all,
                                                 gam, bet, mp, out, t);
    }
}